// Round 2
// baseline (575.824 us; speedup 1.0000x reference)
//
#include <hip/hip_runtime.h>
#include <math.h>

constexpr int B_ = 2, S_ = 2048, D_ = 2048, NH_ = 16, NKV_ = 4, HD_ = 128;
constexpr int EQKV_ = (NH_ + 2 * NKV_) * HD_;   // 3072
constexpr int M_ = B_ * S_;                     // 4096
constexpr float EPS_ = 1e-6f;
constexpr float QSCALE_ = 0.08838834764831845f; // 1/sqrt(HD)

typedef __attribute__((ext_vector_type(8))) short bf16x8;
typedef __attribute__((ext_vector_type(4))) float f32x4;
typedef __attribute__((address_space(1))) unsigned int gu32;
typedef __attribute__((address_space(3))) unsigned int lu32;

__device__ inline ushort f2bf(float f) {   // RNE fp32->bf16 (finite inputs)
    unsigned u = __float_as_uint(f);
    return (ushort)((u + 0x7FFF + ((u >> 16) & 1)) >> 16);
}

// ---------------- pack: fp32 -> bf16, float4 per thread --------------------
__global__ __launch_bounds__(256) void pack_bf16(
    const float* __restrict__ in, ushort* __restrict__ out, int n4)
{
    int i = blockIdx.x * 256 + threadIdx.x;
    if (i >= n4) return;
    float4 f = ((const float4*)in)[i];
    ushort4 u;
    u.x = f2bf(f.x); u.y = f2bf(f.y); u.z = f2bf(f.z); u.w = f2bf(f.w);
    ((ushort4*)out)[i] = u;
}

// ------- K1/K4: C[m,n] = sum_k A[m,k]*W[n,k], bf16 MFMA (m97 structure) ----
__global__ __launch_bounds__(256) void gemm_nt_bf16(
    const ushort* __restrict__ A, const ushort* __restrict__ W,
    float* __restrict__ C, int M, int N, int K)
{
    __shared__ ushort As[128 * 32];
    __shared__ ushort Bs[128 * 32];
    const int t = threadIdx.x;
    const int wave = t >> 6, lane = t & 63;
    const int m0 = blockIdx.y * 128, n0 = blockIdx.x * 128;
    const int wm = (wave >> 1) * 64, wn = (wave & 1) * 64;
    const int lrow = lane & 15, lquad = lane >> 4;

    f32x4 acc[4][4];
#pragma unroll
    for (int i = 0; i < 4; ++i)
#pragma unroll
        for (int j = 0; j < 4; ++j) acc[i][j] = (f32x4){0.f, 0.f, 0.f, 0.f};

    for (int k0 = 0; k0 < K; k0 += 32) {
        __syncthreads();
#pragma unroll
        for (int i = 0; i < 2; ++i) {
            int chunk = t + 256 * i;
            int row = chunk >> 2, seg = chunk & 3;
            int ubase = (wave * 64 + 256 * i) * 8;
            __builtin_amdgcn_global_load_lds(
                (const gu32*)(A + (size_t)(m0 + row) * K + k0 + seg * 8),
                (lu32*)(As + ubase), 16, 0, 0);
            __builtin_amdgcn_global_load_lds(
                (const gu32*)(W + (size_t)(n0 + row) * K + k0 + seg * 8),
                (lu32*)(Bs + ubase), 16, 0, 0);
        }
        __syncthreads();

        bf16x8 af[4], bf[4];
#pragma unroll
        for (int i = 0; i < 4; ++i) {
            af[i] = *(const bf16x8*)(As + (wm + i * 16 + lrow) * 32 + lquad * 8);
            bf[i] = *(const bf16x8*)(Bs + (wn + i * 16 + lrow) * 32 + lquad * 8);
        }
#pragma unroll
        for (int i = 0; i < 4; ++i)
#pragma unroll
            for (int j = 0; j < 4; ++j)
                acc[i][j] = __builtin_amdgcn_mfma_f32_16x16x32_bf16(
                    af[i], bf[j], acc[i][j], 0, 0, 0);
    }
#pragma unroll
    for (int i = 0; i < 4; ++i)
#pragma unroll
        for (int j = 0; j < 4; ++j) {
            float* cp = C + (size_t)(m0 + wm + i * 16 + lquad * 4) * N
                          + n0 + wn + j * 16 + lrow;
#pragma unroll
            for (int r = 0; r < 4; ++r) cp[(size_t)r * N] = acc[i][j][r];
        }
}

// ------ K2: RMSNorm + RoPE + scale + bf16 + transpose; V emitted as V^T ----
// qo (b,NH,s,d) bf16 ; ko (b,NKV,s,d) bf16 ; vo (b,NKV,d,s) bf16 TRANSPOSED
__global__ __launch_bounds__(128) void norm_rope(
    const float* __restrict__ qkv, const float* __restrict__ freqs,
    const float* __restrict__ qw, const float* __restrict__ kw,
    ushort* __restrict__ qo, ushort* __restrict__ ko, ushort* __restrict__ vo)
{
    const int bs = blockIdx.x;
    const int head = blockIdx.y;        // [0,16)=q, [16,20)=k, [20,24)=v
    const int d = threadIdx.x;
    const int b = bs >> 11, s = bs & (S_ - 1);
    const float x = qkv[(size_t)bs * EQKV_ + head * HD_ + d];

    if (head >= NH_ + NKV_) {           // V: bf16 + transpose to (b,kvh,d,s)
        const int vh = head - (NH_ + NKV_);
        vo[((size_t)(b * NKV_ + vh) * HD_ + d) * S_ + s] = f2bf(x);
        return;
    }
    __shared__ float wsum[2];
    float sq = x * x;
#pragma unroll
    for (int off = 1; off < 64; off <<= 1) sq += __shfl_xor(sq, off);
    if ((threadIdx.x & 63) == 0) wsum[threadIdx.x >> 6] = sq;
    __syncthreads();
    const float rs = rsqrtf((wsum[0] + wsum[1]) * (1.0f / HD_) + EPS_);
    const bool isq = head < NH_;
    const float w = isq ? qw[d] : kw[d];
    const float xn = x * rs * w;
    const float other = __shfl_xor(xn, 1);
    const float fr = freqs[s * HD_ + (d & ~1)];
    const float fi = freqs[s * HD_ + (d & ~1) + 1];
    float out = (d & 1) ? fmaf(xn, fr, other * fi)
                        : fmaf(xn, fr, -other * fi);
    if (isq) {
        out *= QSCALE_;
        qo[((size_t)(b * NH_ + head) * S_ + s) * HD_ + d] = f2bf(out);
    } else {
        const int kh = head - NH_;
        ko[((size_t)(b * NKV_ + kh) * S_ + s) * HD_ + d] = f2bf(out);
    }
}

// ------------- K3: causal flash attention, bf16 MFMA ----------------------
// grid (32, NH, B), block 256 = 4 waves. Q tile 64 (16 q-rows/wave), KV 64.
// v3: register-staged K/V prefetch (T14) + single-buffer LDS (42 KB -> 3
//     blocks/CU), defer-max softmax (T13, THR=8: no per-tile row reduce in
//     the common path), per-lane l partials (one reduce at epilogue),
//     explicit swizzled ds_write (write slot == read slot XOR), setprio.
__global__ __launch_bounds__(256, 3) void flash_attn_mfma(
    const ushort* __restrict__ Q,   // (B,NH,S,HD) bf16, pre-scaled by 1/sqrt(HD)
    const ushort* __restrict__ K,   // (B,NKV,S,HD) bf16
    const ushort* __restrict__ V,   // (B,NKV,HD,S) bf16 -- transposed
    ushort* __restrict__ Y)         // (B,S,NH*HD) bf16
{
    __shared__ __align__(16) ushort Ks[4 * 64 * 32];   // [kstep][kv][32] 16 KB
    __shared__ __align__(16) ushort Vs[2 * 128 * 32];  // [kks][d][32]    16 KB
    __shared__ __align__(16) ushort Ps[4 * 16 * 72];   // per-wave P       9 KB

    const int t = threadIdx.x, w = t >> 6, lane = t & 63;
    const int lx = lane & 15, quad = lane >> 4;
    const int h = blockIdx.y, b = blockIdx.z;
    const int qt = (int)gridDim.x - 1 - (int)blockIdx.x;  // heavy blocks first
    const int q0 = qt * 64;
    const int kvh = h >> 2;
    const int srow = lane >> 2, sseg = lane & 3;          // staging row/seg
    // Swizzle f(row) = (row&15)>>1 & 3, applied on BOTH ds_write and ds_read
    // slot index (rule #21: same involution both sides).
    const int wslot = (sseg ^ ((srow >> 1) & 3)) * 8;     // write slot (u16)
    const int rslot = (quad ^ ((lx >> 1) & 3)) * 8;       // read slot (u16)

    const ushort* qb = Q + ((size_t)(b * NH_ + h) * S_ + q0) * HD_;
    const ushort* kb = K + ((size_t)(b * NKV_ + kvh) * S_ + w * 16 + srow) * HD_
                         + sseg * 8;
    const ushort* vb = V + ((size_t)(b * NKV_ + kvh) * HD_) * S_;

    // Q A-fragments: rows w*16+lx, k = ks*32 + quad*8 .. +8  (kept in regs)
    bf16x8 aq[4];
#pragma unroll
    for (int ks = 0; ks < 4; ++ks)
        aq[ks] = *(const bf16x8*)(qb + (size_t)(w * 16 + lx) * HD_ + ks * 32 + quad * 8);

    f32x4 o[8];
#pragma unroll
    for (int j = 0; j < 8; ++j) o[j] = (f32x4){0.f, 0.f, 0.f, 0.f};
    float mrow[4] = {-INFINITY, -INFINITY, -INFINITY, -INFINITY};
    float lp[4] = {0.f, 0.f, 0.f, 0.f};   // per-lane l partials (4 cols each)

    // T14 register staging: 8x16B per lane per tile (4 K + 4 V)
    uint4 kreg[4], vreg[4];
    auto issue_loads = [&](int k0s) {
#pragma unroll
        for (int i = 0; i < 4; ++i)
            kreg[i] = *(const uint4*)(kb + (size_t)k0s * HD_ + i * 32);
#pragma unroll
        for (int i = 0; i < 4; ++i) {
            const int kks = i >> 1, hf = i & 1;
            const int dr = hf * 64 + w * 16 + srow;
            vreg[i] = *(const uint4*)(vb + (size_t)dr * S_ + k0s + kks * 32 + sseg * 8);
        }
    };
    auto stage_writes = [&]() {
#pragma unroll
        for (int i = 0; i < 4; ++i)
            *(uint4*)(Ks + i * 2048 + w * 512 + srow * 32 + wslot) = kreg[i];
#pragma unroll
        for (int i = 0; i < 4; ++i) {
            const int kks = i >> 1, hf = i & 1;
            const int dr = hf * 64 + w * 16 + srow;
            *(uint4*)(Vs + kks * 4096 + dr * 32 + wslot) = vreg[i];
        }
    };

    const int ntiles = qt + 1;
    issue_loads(0);                        // prologue: tile 0 -> regs

    for (int tk = 0; tk < ntiles; ++tk) {
        const int k0 = tk * 64;
        asm volatile("s_barrier" ::: "memory");   // all waves done reading LDS
        stage_writes();                    // compiler waits vmcnt on kreg/vreg
        asm volatile("s_waitcnt lgkmcnt(0)" ::: "memory");
        asm volatile("s_barrier" ::: "memory");   // tile tk staged everywhere

        if (tk + 1 < ntiles) issue_loads(k0 + 64);  // prefetch hides under compute

        // ---- S = Q K^T : wave slab 16q x 64k, C-layout ----
        f32x4 s[4];
#pragma unroll
        for (int j = 0; j < 4; ++j) s[j] = (f32x4){0.f, 0.f, 0.f, 0.f};
        __builtin_amdgcn_s_setprio(1);
#pragma unroll
        for (int ks = 0; ks < 4; ++ks) {
#pragma unroll
            for (int j = 0; j < 4; ++j) {
                bf16x8 bk = *(const bf16x8*)(Ks + ks * 2048 + (j * 16 + lx) * 32 + rslot);
                s[j] = __builtin_amdgcn_mfma_f32_16x16x32_bf16(aq[ks], bk, s[j], 0, 0, 0);
            }
        }
        __builtin_amdgcn_s_setprio(0);

        // ---- causal mask (diagonal tile only) ----
        const int qrow_base = q0 + w * 16 + quad * 4;
        if (tk == ntiles - 1) {
#pragma unroll
            for (int reg = 0; reg < 4; ++reg) {
                const int qrow = qrow_base + reg;
#pragma unroll
                for (int j = 0; j < 4; ++j)
                    if (k0 + lx + 16 * j > qrow) s[j][reg] = -INFINITY;
            }
        }

        // ---- online softmax, defer-max (T13, THR=8) ----
        float rmx[4];
        bool need = false;
#pragma unroll
        for (int reg = 0; reg < 4; ++reg) {
            rmx[reg] = fmaxf(fmaxf(s[0][reg], s[1][reg]),
                             fmaxf(s[2][reg], s[3][reg]));
            need |= (rmx[reg] > mrow[reg] + 8.0f);
        }
        if (__any(need)) {                 // rare: ~once per block
#pragma unroll
            for (int reg = 0; reg < 4; ++reg) {
                float rm = rmx[reg];
#pragma unroll
                for (int off = 1; off < 16; off <<= 1)
                    rm = fmaxf(rm, __shfl_xor(rm, off));
                const float mn = fmaxf(mrow[reg], rm);
                const float alpha = __expf(mrow[reg] - mn);
                mrow[reg] = mn;
                lp[reg] *= alpha;
#pragma unroll
                for (int j = 0; j < 8; ++j) o[j][reg] *= alpha;
            }
        }
        // common path: p = exp(s - mrow) (<= e^8), no shuffles
#pragma unroll
        for (int reg = 0; reg < 4; ++reg) {
#pragma unroll
            for (int j = 0; j < 4; ++j) {
                const float p = __expf(s[j][reg] - mrow[reg]);
                lp[reg] += p;
                Ps[w * 1152 + (quad * 4 + reg) * 72 + lx + 16 * j] = f2bf(p);
            }
        }

        // ---- O += P V : P A-frags from LDS, V^T B-frags ----
        bf16x8 ap[2];
#pragma unroll
        for (int ks2 = 0; ks2 < 2; ++ks2)
            ap[ks2] = *(const bf16x8*)(Ps + w * 1152 + lx * 72 + ks2 * 32 + quad * 8);
        __builtin_amdgcn_s_setprio(1);
#pragma unroll
        for (int jd = 0; jd < 8; ++jd) {
#pragma unroll
            for (int ks2 = 0; ks2 < 2; ++ks2) {
                bf16x8 bv = *(const bf16x8*)(Vs + ks2 * 4096 + (jd * 16 + lx) * 32 + rslot);
                o[jd] = __builtin_amdgcn_mfma_f32_16x16x32_bf16(ap[ks2], bv, o[jd], 0, 0, 0);
            }
        }
        __builtin_amdgcn_s_setprio(0);
    }

    // ---- epilogue: reduce l partials across the 16-lane row group ----
#pragma unroll
    for (int reg = 0; reg < 4; ++reg) {
        float l = lp[reg];
#pragma unroll
        for (int off = 1; off < 16; off <<= 1) l += __shfl_xor(l, off);
        const float inv = 1.0f / l;
        const size_t yb = (size_t)(b * S_ + q0 + w * 16 + quad * 4 + reg) * (NH_ * HD_)
                        + h * HD_ + lx;
#pragma unroll
        for (int jd = 0; jd < 8; ++jd)
            Y[yb + jd * 16] = f2bf(o[jd][reg] * inv);
    }
}

extern "C" void kernel_launch(void* const* d_in, const int* in_sizes, int n_in,
                              void* d_out, int out_size, void* d_ws, size_t ws_size,
                              hipStream_t stream)
{
    const float* x     = (const float*)d_in[0];
    const float* freqs = (const float*)d_in[1];
    const float* wqkv  = (const float*)d_in[2];
    const float* wo    = (const float*)d_in[3];
    const float* qw    = (const float*)d_in[4];
    const float* kw    = (const float*)d_in[5];
    float* out = (float*)d_out;

    // ws layout (100,663,296 B total, byte offsets; liveness-checked):
    //   [0..50.33M)      qkv fp32 (K1 out, norm_rope in); later wobf@0 (8.39M)
    //                    + ybf@8.39M (16.78M) after norm_rope consumes qkv
    //   [50.33M..62.91M) wqkvbf (K1 in only); later qbf@50.33M (16.78M)
    //   [67.11M..71.30M) kbf ; [71.30M..75.50M) vtb (transposed V)
    //   [83.89M..100.66M) xbf (K1 in only)
    char* ws = (char*)d_ws;
    float*  qkv    = (float*)ws;
    ushort* wqkvbf = (ushort*)(ws + 50331648);
    ushort* xbf    = (ushort*)(ws + 83886080);
    ushort* qbf    = (ushort*)(ws + 50331648);
    ushort* kbf    = (ushort*)(ws + 67108864);
    ushort* vtb    = (ushort*)(ws + 71303168);
    ushort* wobf   = (ushort*)(ws + 0);
    ushort* ybf    = (ushort*)(ws + 8388608);

    pack_bf16<<<(M_ * D_ / 4 + 255) / 256, 256, 0, stream>>>(x, xbf, M_ * D_ / 4);
    pack_bf16<<<(EQKV_ * D_ / 4 + 255) / 256, 256, 0, stream>>>(wqkv, wqkvbf,
                                                                EQKV_ * D_ / 4);
    // K1: qkv = x @ wqkv^T  (bf16 MFMA, fp32 out)
    gemm_nt_bf16<<<dim3(EQKV_ / 128, M_ / 128), 256, 0, stream>>>(
        xbf, wqkvbf, qkv, M_, EQKV_, D_);
    // K2: rmsnorm + rope -> bf16 q/k + transposed bf16 V (overwrites wqkvbf)
    norm_rope<<<dim3(M_, NH_ + 2 * NKV_), 128, 0, stream>>>(qkv, freqs, qw, kw,
                                                            qbf, kbf, vtb);
    // pack wo into dead qkv region
    pack_bf16<<<(D_ * NH_ * HD_ / 4 + 255) / 256, 256, 0, stream>>>(
        wo, wobf, D_ * NH_ * HD_ / 4);
    // K3: MFMA flash attention -> ybf
    flash_attn_mfma<<<dim3(S_ / 64, NH_, B_), 256, 0, stream>>>(qbf, kbf, vtb, ybf);
    // K4: out = y @ wo^T  (bf16 MFMA)
    gemm_nt_bf16<<<dim3(D_ / 128, M_ / 128), 256, 0, stream>>>(
        ybf, wobf, out, M_, D_, NH_ * HD_);
}

// Round 3
// 400.214 us; speedup vs baseline: 1.4388x; 1.4388x over previous
//
#include <hip/hip_runtime.h>
#include <math.h>

constexpr int B_ = 2, S_ = 2048, D_ = 2048, NH_ = 16, NKV_ = 4, HD_ = 128;
constexpr int EQKV_ = (NH_ + 2 * NKV_) * HD_;   // 3072
constexpr int M_ = B_ * S_;                     // 4096
constexpr float EPS_ = 1e-6f;
constexpr float QSCALE_ = 0.08838834764831845f; // 1/sqrt(HD)

typedef __attribute__((ext_vector_type(8))) short bf16x8;
typedef __attribute__((ext_vector_type(4))) float f32x4;
typedef __attribute__((address_space(1))) unsigned int gu32;
typedef __attribute__((address_space(3))) unsigned int lu32;

__device__ inline ushort f2bf(float f) {   // RNE fp32->bf16 (finite inputs)
    unsigned u = __float_as_uint(f);
    return (ushort)((u + 0x7FFF + ((u >> 16) & 1)) >> 16);
}

// ---------------- pack: fp32 -> bf16, float4 per thread --------------------
__global__ __launch_bounds__(256) void pack_bf16(
    const float* __restrict__ in, ushort* __restrict__ out, int n4)
{
    int i = blockIdx.x * 256 + threadIdx.x;
    if (i >= n4) return;
    float4 f = ((const float4*)in)[i];
    ushort4 u;
    u.x = f2bf(f.x); u.y = f2bf(f.y); u.z = f2bf(f.z); u.w = f2bf(f.w);
    ((ushort4*)out)[i] = u;
}

// ------- K1/K4: C[m,n] = sum_k A[m,k]*W[n,k], bf16 MFMA (m97 structure) ----
__global__ __launch_bounds__(256) void gemm_nt_bf16(
    const ushort* __restrict__ A, const ushort* __restrict__ W,
    float* __restrict__ C, int M, int N, int K)
{
    __shared__ ushort As[128 * 32];
    __shared__ ushort Bs[128 * 32];
    const int t = threadIdx.x;
    const int wave = t >> 6, lane = t & 63;
    const int m0 = blockIdx.y * 128, n0 = blockIdx.x * 128;
    const int wm = (wave >> 1) * 64, wn = (wave & 1) * 64;
    const int lrow = lane & 15, lquad = lane >> 4;

    f32x4 acc[4][4];
#pragma unroll
    for (int i = 0; i < 4; ++i)
#pragma unroll
        for (int j = 0; j < 4; ++j) acc[i][j] = (f32x4){0.f, 0.f, 0.f, 0.f};

    for (int k0 = 0; k0 < K; k0 += 32) {
        __syncthreads();
#pragma unroll
        for (int i = 0; i < 2; ++i) {
            int chunk = t + 256 * i;
            int row = chunk >> 2, seg = chunk & 3;
            int ubase = (wave * 64 + 256 * i) * 8;
            __builtin_amdgcn_global_load_lds(
                (const gu32*)(A + (size_t)(m0 + row) * K + k0 + seg * 8),
                (lu32*)(As + ubase), 16, 0, 0);
            __builtin_amdgcn_global_load_lds(
                (const gu32*)(W + (size_t)(n0 + row) * K + k0 + seg * 8),
                (lu32*)(Bs + ubase), 16, 0, 0);
        }
        __syncthreads();

        bf16x8 af[4], bf[4];
#pragma unroll
        for (int i = 0; i < 4; ++i) {
            af[i] = *(const bf16x8*)(As + (wm + i * 16 + lrow) * 32 + lquad * 8);
            bf[i] = *(const bf16x8*)(Bs + (wn + i * 16 + lrow) * 32 + lquad * 8);
        }
#pragma unroll
        for (int i = 0; i < 4; ++i)
#pragma unroll
            for (int j = 0; j < 4; ++j)
                acc[i][j] = __builtin_amdgcn_mfma_f32_16x16x32_bf16(
                    af[i], bf[j], acc[i][j], 0, 0, 0);
    }
#pragma unroll
    for (int i = 0; i < 4; ++i)
#pragma unroll
        for (int j = 0; j < 4; ++j) {
            float* cp = C + (size_t)(m0 + wm + i * 16 + lquad * 4) * N
                          + n0 + wn + j * 16 + lrow;
#pragma unroll
            for (int r = 0; r < 4; ++r) cp[(size_t)r * N] = acc[i][j][r];
        }
}

// ------ K2: RMSNorm + RoPE + scale + bf16 + transpose; V emitted as V^T ----
// qo (b,NH,s,d) bf16 ; ko (b,NKV,s,d) bf16 ; vo (b,NKV,d,s) bf16 TRANSPOSED
__global__ __launch_bounds__(128) void norm_rope(
    const float* __restrict__ qkv, const float* __restrict__ freqs,
    const float* __restrict__ qw, const float* __restrict__ kw,
    ushort* __restrict__ qo, ushort* __restrict__ ko, ushort* __restrict__ vo)
{
    const int bs = blockIdx.x;
    const int head = blockIdx.y;        // [0,16)=q, [16,20)=k, [20,24)=v
    const int d = threadIdx.x;
    const int b = bs >> 11, s = bs & (S_ - 1);
    const float x = qkv[(size_t)bs * EQKV_ + head * HD_ + d];

    if (head >= NH_ + NKV_) {           // V: bf16 + transpose to (b,kvh,d,s)
        const int vh = head - (NH_ + NKV_);
        vo[((size_t)(b * NKV_ + vh) * HD_ + d) * S_ + s] = f2bf(x);
        return;
    }
    __shared__ float wsum[2];
    float sq = x * x;
#pragma unroll
    for (int off = 1; off < 64; off <<= 1) sq += __shfl_xor(sq, off);
    if ((threadIdx.x & 63) == 0) wsum[threadIdx.x >> 6] = sq;
    __syncthreads();
    const float rs = rsqrtf((wsum[0] + wsum[1]) * (1.0f / HD_) + EPS_);
    const bool isq = head < NH_;
    const float w = isq ? qw[d] : kw[d];
    const float xn = x * rs * w;
    const float other = __shfl_xor(xn, 1);
    const float fr = freqs[s * HD_ + (d & ~1)];
    const float fi = freqs[s * HD_ + (d & ~1) + 1];
    float out = (d & 1) ? fmaf(xn, fr, other * fi)
                        : fmaf(xn, fr, -other * fi);
    if (isq) {
        out *= QSCALE_;
        qo[((size_t)(b * NH_ + head) * S_ + s) * HD_ + d] = f2bf(out);
    } else {
        const int kh = head - NH_;
        ko[((size_t)(b * NKV_ + kh) * S_ + s) * HD_ + d] = f2bf(out);
    }
}

// ------------- K3: causal flash attention, bf16 MFMA ----------------------
// grid (32, NH, B), block 256 = 4 waves. Q tile 64 (16 q-rows/wave), KV 64.
// v4: v3 with the scratch-spill fixed -- NO lambdas, NO staging arrays.
//     8 individually-named uint4 staging registers, straight-line code,
//     all LDS addresses as compile-time offsets from hoisted bases.
__global__ __launch_bounds__(256, 3) void flash_attn_mfma(
    const ushort* __restrict__ Q,   // (B,NH,S,HD) bf16, pre-scaled by 1/sqrt(HD)
    const ushort* __restrict__ K,   // (B,NKV,S,HD) bf16
    const ushort* __restrict__ V,   // (B,NKV,HD,S) bf16 -- transposed
    ushort* __restrict__ Y)         // (B,S,NH*HD) bf16
{
    __shared__ __align__(16) ushort Ks[4 * 64 * 32];   // [kstep][kv][32] 16 KB
    __shared__ __align__(16) ushort Vs[2 * 128 * 32];  // [kks][d][32]    16 KB
    __shared__ __align__(16) ushort Ps[4 * 16 * 72];   // per-wave P       9 KB

    const int t = threadIdx.x, w = t >> 6, lane = t & 63;
    const int lx = lane & 15, quad = lane >> 4;
    const int h = blockIdx.y, b = blockIdx.z;
    const int qt = (int)gridDim.x - 1 - (int)blockIdx.x;  // heavy blocks first
    const int q0 = qt * 64;
    const int kvh = h >> 2;
    const int srow = lane >> 2, sseg = lane & 3;          // staging row/seg
    // Swizzle f(row) = (row>>1)&3, applied on BOTH ds_write and ds_read
    // slot index (rule #21: same involution both sides).
    const int wslot = (sseg ^ ((srow >> 1) & 3)) * 8;     // write slot (u16)
    const int rslot = (quad ^ ((lx >> 1) & 3)) * 8;       // read slot (u16)

    const ushort* qb = Q + ((size_t)(b * NH_ + h) * S_ + q0) * HD_;
    // K source: row (w*16+srow), seg sseg -> advance by k0*HD_ each tile
    const ushort* ksrc = K + ((size_t)(b * NKV_ + kvh) * S_ + w * 16 + srow) * HD_
                           + sseg * 8;
    // V^T sources: rows (w*16+srow) and (64+w*16+srow) -> advance by k0
    const ushort* vb = V + ((size_t)(b * NKV_ + kvh) * HD_) * S_;
    const ushort* vsrc0 = vb + (size_t)(w * 16 + srow) * S_ + sseg * 8;
    const ushort* vsrc1 = vb + (size_t)(64 + w * 16 + srow) * S_ + sseg * 8;
    // LDS staging destinations (compile-time offsets from these)
    ushort* kdst = Ks + w * 512 + srow * 32 + wslot;            // +i*2048
    ushort* vdst0 = Vs + (w * 16 + srow) * 32 + wslot;          // +kks*4096
    ushort* vdst1 = Vs + (64 + w * 16 + srow) * 32 + wslot;     // +kks*4096

    // Q A-fragments: rows w*16+lx, k = ks*32 + quad*8 .. +8  (kept in regs)
    bf16x8 aq[4];
#pragma unroll
    for (int ks = 0; ks < 4; ++ks)
        aq[ks] = *(const bf16x8*)(qb + (size_t)(w * 16 + lx) * HD_ + ks * 32 + quad * 8);

    f32x4 o[8];
#pragma unroll
    for (int j = 0; j < 8; ++j) o[j] = (f32x4){0.f, 0.f, 0.f, 0.f};
    float mrow[4] = {-INFINITY, -INFINITY, -INFINITY, -INFINITY};
    float lp[4] = {0.f, 0.f, 0.f, 0.f};   // per-lane l partials (4 cols each)

    // T14 staging registers: named scalars only (no arrays -> no scratch)
    uint4 kr0, kr1, kr2, kr3, vr0, vr1, vr2, vr3;

    // prologue: issue tile-0 loads
    kr0 = *(const uint4*)(ksrc +  0);
    kr1 = *(const uint4*)(ksrc + 32);
    kr2 = *(const uint4*)(ksrc + 64);
    kr3 = *(const uint4*)(ksrc + 96);
    vr0 = *(const uint4*)(vsrc0 +  0);
    vr1 = *(const uint4*)(vsrc1 +  0);
    vr2 = *(const uint4*)(vsrc0 + 32);
    vr3 = *(const uint4*)(vsrc1 + 32);

    const int ntiles = qt + 1;
    for (int tk = 0; tk < ntiles; ++tk) {
        const int k0 = tk * 64;
        asm volatile("s_barrier" ::: "memory");   // all waves done reading LDS
        // stage current tile (compiler inserts vmcnt waits on kr*/vr*)
        *(uint4*)(kdst +    0) = kr0;
        *(uint4*)(kdst + 2048) = kr1;
        *(uint4*)(kdst + 4096) = kr2;
        *(uint4*)(kdst + 6144) = kr3;
        *(uint4*)(vdst0 +    0) = vr0;
        *(uint4*)(vdst1 +    0) = vr1;
        *(uint4*)(vdst0 + 4096) = vr2;
        *(uint4*)(vdst1 + 4096) = vr3;
        asm volatile("s_waitcnt lgkmcnt(0)" ::: "memory");
        asm volatile("s_barrier" ::: "memory");   // tile tk staged everywhere

        if (tk + 1 < ntiles) {                    // prefetch next tile -> regs
            const size_t ko8 = (size_t)(k0 + 64);
            kr0 = *(const uint4*)(ksrc + ko8 * HD_ +  0);
            kr1 = *(const uint4*)(ksrc + ko8 * HD_ + 32);
            kr2 = *(const uint4*)(ksrc + ko8 * HD_ + 64);
            kr3 = *(const uint4*)(ksrc + ko8 * HD_ + 96);
            vr0 = *(const uint4*)(vsrc0 + ko8 +  0);
            vr1 = *(const uint4*)(vsrc1 + ko8 +  0);
            vr2 = *(const uint4*)(vsrc0 + ko8 + 32);
            vr3 = *(const uint4*)(vsrc1 + ko8 + 32);
        }

        // ---- S = Q K^T : wave slab 16q x 64k, C-layout ----
        f32x4 s[4];
#pragma unroll
        for (int j = 0; j < 4; ++j) s[j] = (f32x4){0.f, 0.f, 0.f, 0.f};
        __builtin_amdgcn_s_setprio(1);
#pragma unroll
        for (int ks = 0; ks < 4; ++ks) {
#pragma unroll
            for (int j = 0; j < 4; ++j) {
                bf16x8 bk = *(const bf16x8*)(Ks + ks * 2048 + (j * 16 + lx) * 32 + rslot);
                s[j] = __builtin_amdgcn_mfma_f32_16x16x32_bf16(aq[ks], bk, s[j], 0, 0, 0);
            }
        }
        __builtin_amdgcn_s_setprio(0);

        // ---- causal mask (diagonal tile only) ----
        const int qrow_base = q0 + w * 16 + quad * 4;
        if (tk == ntiles - 1) {
#pragma unroll
            for (int reg = 0; reg < 4; ++reg) {
                const int qrow = qrow_base + reg;
#pragma unroll
                for (int j = 0; j < 4; ++j)
                    if (k0 + lx + 16 * j > qrow) s[j][reg] = -INFINITY;
            }
        }

        // ---- online softmax, defer-max (T13, THR=8) ----
        float rmx[4];
        bool need = false;
#pragma unroll
        for (int reg = 0; reg < 4; ++reg) {
            rmx[reg] = fmaxf(fmaxf(s[0][reg], s[1][reg]),
                             fmaxf(s[2][reg], s[3][reg]));
            need |= (rmx[reg] > mrow[reg] + 8.0f);
        }
        if (__any(need)) {                 // rare: ~once per block
#pragma unroll
            for (int reg = 0; reg < 4; ++reg) {
                float rm = rmx[reg];
#pragma unroll
                for (int off = 1; off < 16; off <<= 1)
                    rm = fmaxf(rm, __shfl_xor(rm, off));
                const float mn = fmaxf(mrow[reg], rm);
                const float alpha = __expf(mrow[reg] - mn);
                mrow[reg] = mn;
                lp[reg] *= alpha;
#pragma unroll
                for (int j = 0; j < 8; ++j) o[j][reg] *= alpha;
            }
        }
        // common path: p = exp(s - mrow) (<= e^8), no shuffles
#pragma unroll
        for (int reg = 0; reg < 4; ++reg) {
#pragma unroll
            for (int j = 0; j < 4; ++j) {
                const float p = __expf(s[j][reg] - mrow[reg]);
                lp[reg] += p;
                Ps[w * 1152 + (quad * 4 + reg) * 72 + lx + 16 * j] = f2bf(p);
            }
        }

        // ---- O += P V : P A-frags from LDS, V^T B-frags ----
        bf16x8 ap[2];
#pragma unroll
        for (int ks2 = 0; ks2 < 2; ++ks2)
            ap[ks2] = *(const bf16x8*)(Ps + w * 1152 + lx * 72 + ks2 * 32 + quad * 8);
        __builtin_amdgcn_s_setprio(1);
#pragma unroll
        for (int jd = 0; jd < 8; ++jd) {
#pragma unroll
            for (int ks2 = 0; ks2 < 2; ++ks2) {
                bf16x8 bv = *(const bf16x8*)(Vs + ks2 * 4096 + (jd * 16 + lx) * 32 + rslot);
                o[jd] = __builtin_amdgcn_mfma_f32_16x16x32_bf16(ap[ks2], bv, o[jd], 0, 0, 0);
            }
        }
        __builtin_amdgcn_s_setprio(0);
    }

    // ---- epilogue: reduce l partials across the 16-lane row group ----
#pragma unroll
    for (int reg = 0; reg < 4; ++reg) {
        float l = lp[reg];
#pragma unroll
        for (int off = 1; off < 16; off <<= 1) l += __shfl_xor(l, off);
        const float inv = 1.0f / l;
        const size_t yb = (size_t)(b * S_ + q0 + w * 16 + quad * 4 + reg) * (NH_ * HD_)
                        + h * HD_ + lx;
#pragma unroll
        for (int jd = 0; jd < 8; ++jd)
            Y[yb + jd * 16] = f2bf(o[jd][reg] * inv);
    }
}

extern "C" void kernel_launch(void* const* d_in, const int* in_sizes, int n_in,
                              void* d_out, int out_size, void* d_ws, size_t ws_size,
                              hipStream_t stream)
{
    const float* x     = (const float*)d_in[0];
    const float* freqs = (const float*)d_in[1];
    const float* wqkv  = (const float*)d_in[2];
    const float* wo    = (const float*)d_in[3];
    const float* qw    = (const float*)d_in[4];
    const float* kw    = (const float*)d_in[5];
    float* out = (float*)d_out;

    // ws layout (100,663,296 B total, byte offsets; liveness-checked):
    //   [0..50.33M)      qkv fp32 (K1 out, norm_rope in); later wobf@0 (8.39M)
    //                    + ybf@8.39M (16.78M) after norm_rope consumes qkv
    //   [50.33M..62.91M) wqkvbf (K1 in only); later qbf@50.33M (16.78M)
    //   [67.11M..71.30M) kbf ; [71.30M..75.50M) vtb (transposed V)
    //   [83.89M..100.66M) xbf (K1 in only)
    char* ws = (char*)d_ws;
    float*  qkv    = (float*)ws;
    ushort* wqkvbf = (ushort*)(ws + 50331648);
    ushort* xbf    = (ushort*)(ws + 83886080);
    ushort* qbf    = (ushort*)(ws + 50331648);
    ushort* kbf    = (ushort*)(ws + 67108864);
    ushort* vtb    = (ushort*)(ws + 71303168);
    ushort* wobf   = (ushort*)(ws + 0);
    ushort* ybf    = (ushort*)(ws + 8388608);

    pack_bf16<<<(M_ * D_ / 4 + 255) / 256, 256, 0, stream>>>(x, xbf, M_ * D_ / 4);
    pack_bf16<<<(EQKV_ * D_ / 4 + 255) / 256, 256, 0, stream>>>(wqkv, wqkvbf,
                                                                EQKV_ * D_ / 4);
    // K1: qkv = x @ wqkv^T  (bf16 MFMA, fp32 out)
    gemm_nt_bf16<<<dim3(EQKV_ / 128, M_ / 128), 256, 0, stream>>>(
        xbf, wqkvbf, qkv, M_, EQKV_, D_);
    // K2: rmsnorm + rope -> bf16 q/k + transposed bf16 V (overwrites wqkvbf)
    norm_rope<<<dim3(M_, NH_ + 2 * NKV_), 128, 0, stream>>>(qkv, freqs, qw, kw,
                                                            qbf, kbf, vtb);
    // pack wo into dead qkv region
    pack_bf16<<<(D_ * NH_ * HD_ / 4 + 255) / 256, 256, 0, stream>>>(
        wo, wobf, D_ * NH_ * HD_ / 4);
    // K3: MFMA flash attention -> ybf
    flash_attn_mfma<<<dim3(S_ / 64, NH_, B_), 256, 0, stream>>>(qbf, kbf, vtb, ybf);
    // K4: out = y @ wo^T  (bf16 MFMA)
    gemm_nt_bf16<<<dim3(D_ / 128, M_ / 128), 256, 0, stream>>>(
        ybf, wobf, out, M_, D_, NH_ * HD_);
}

// Round 4
// 366.195 us; speedup vs baseline: 1.5725x; 1.0929x over previous
//
#include <hip/hip_runtime.h>
#include <math.h>

constexpr int B_ = 2, S_ = 2048, D_ = 2048, NH_ = 16, NKV_ = 4, HD_ = 128;
constexpr int EQKV_ = (NH_ + 2 * NKV_) * HD_;   // 3072
constexpr int M_ = B_ * S_;                     // 4096
constexpr float EPS_ = 1e-6f;
constexpr float QSCALE_ = 0.08838834764831845f; // 1/sqrt(HD)

typedef __attribute__((ext_vector_type(8))) short bf16x8;
typedef __attribute__((ext_vector_type(4))) float f32x4;
typedef __attribute__((address_space(1))) unsigned int gu32;
typedef __attribute__((address_space(3))) unsigned int lu32;

__device__ inline ushort f2bf(float f) {   // RNE fp32->bf16 (finite inputs)
    unsigned u = __float_as_uint(f);
    return (ushort)((u + 0x7FFF + ((u >> 16) & 1)) >> 16);
}

// ---------------- pack: fp32 -> bf16, float4 per thread --------------------
__global__ __launch_bounds__(256) void pack_bf16(
    const float* __restrict__ in, ushort* __restrict__ out, int n4)
{
    int i = blockIdx.x * 256 + threadIdx.x;
    if (i >= n4) return;
    float4 f = ((const float4*)in)[i];
    ushort4 u;
    u.x = f2bf(f.x); u.y = f2bf(f.y); u.z = f2bf(f.z); u.w = f2bf(f.w);
    ((ushort4*)out)[i] = u;
}

// ------- K4: C[m,n] = sum_k A[m,k]*W[n,k], bf16 MFMA (m97 structure) -------
__global__ __launch_bounds__(256) void gemm_nt_bf16(
    const ushort* __restrict__ A, const ushort* __restrict__ W,
    float* __restrict__ C, int M, int N, int K)
{
    __shared__ ushort As[128 * 32];
    __shared__ ushort Bs[128 * 32];
    const int t = threadIdx.x;
    const int wave = t >> 6, lane = t & 63;
    const int m0 = blockIdx.y * 128, n0 = blockIdx.x * 128;
    const int wm = (wave >> 1) * 64, wn = (wave & 1) * 64;
    const int lrow = lane & 15, lquad = lane >> 4;

    f32x4 acc[4][4];
#pragma unroll
    for (int i = 0; i < 4; ++i)
#pragma unroll
        for (int j = 0; j < 4; ++j) acc[i][j] = (f32x4){0.f, 0.f, 0.f, 0.f};

    for (int k0 = 0; k0 < K; k0 += 32) {
        __syncthreads();
#pragma unroll
        for (int i = 0; i < 2; ++i) {
            int chunk = t + 256 * i;
            int row = chunk >> 2, seg = chunk & 3;
            int ubase = (wave * 64 + 256 * i) * 8;
            __builtin_amdgcn_global_load_lds(
                (const gu32*)(A + (size_t)(m0 + row) * K + k0 + seg * 8),
                (lu32*)(As + ubase), 16, 0, 0);
            __builtin_amdgcn_global_load_lds(
                (const gu32*)(W + (size_t)(n0 + row) * K + k0 + seg * 8),
                (lu32*)(Bs + ubase), 16, 0, 0);
        }
        __syncthreads();

        bf16x8 af[4], bf[4];
#pragma unroll
        for (int i = 0; i < 4; ++i) {
            af[i] = *(const bf16x8*)(As + (wm + i * 16 + lrow) * 32 + lquad * 8);
            bf[i] = *(const bf16x8*)(Bs + (wn + i * 16 + lrow) * 32 + lquad * 8);
        }
#pragma unroll
        for (int i = 0; i < 4; ++i)
#pragma unroll
            for (int j = 0; j < 4; ++j)
                acc[i][j] = __builtin_amdgcn_mfma_f32_16x16x32_bf16(
                    af[i], bf[j], acc[i][j], 0, 0, 0);
    }
#pragma unroll
    for (int i = 0; i < 4; ++i)
#pragma unroll
        for (int j = 0; j < 4; ++j) {
            float* cp = C + (size_t)(m0 + wm + i * 16 + lquad * 4) * N
                          + n0 + wn + j * 16 + lrow;
#pragma unroll
            for (int r = 0; r < 4; ++r) cp[(size_t)r * N] = acc[i][j][r];
        }
}

// --- K1 fused: qkv GEMM + RMSNorm + RoPE + scale + bf16 + V^T, no fp32 C ---
// N = 3072 = 24 head-aligned tiles of 128 cols; RMSNorm axis == tile cols.
// Outputs: qo (b,NH,s,d) pre-scaled; ko (b,NKV,s,d); vo (b,NKV,d,s) = V^T.
__global__ __launch_bounds__(256) void gemm_qkv_fused(
    const ushort* __restrict__ A,   // xbf (M,K) bf16
    const ushort* __restrict__ W,   // wqkvbf (EQKV,K) bf16
    const float* __restrict__ freqs,
    const float* __restrict__ qw, const float* __restrict__ kw,
    ushort* __restrict__ qo, ushort* __restrict__ ko, ushort* __restrict__ vo,
    int K)
{
    __shared__ __align__(16) ushort smem[128 * 136];  // As|Bs during K-loop; Lt after
    __shared__ float rsbuf[256];
    ushort* As = smem;            // 128*32
    ushort* Bs = smem + 4096;     // 128*32
    ushort* Lt = smem;            // [128][136] u16 staging tile (post-loop)

    const int t = threadIdx.x;
    const int wave = t >> 6, lane = t & 63;
    const int m0 = blockIdx.y * 128, n0 = blockIdx.x * 128;
    const int wm = (wave >> 1) * 64, wn = (wave & 1) * 64;
    const int half = wave & 1;                 // which 64-col half this wave owns
    const int lrow = lane & 15, lquad = lane >> 4;
    const int head = n0 >> 7;                  // block-uniform: [0,16)q [16,20)k [20,24)v
    const int b = m0 >> 11, s0 = m0 & (S_ - 1);

    f32x4 acc[4][4];
#pragma unroll
    for (int i = 0; i < 4; ++i)
#pragma unroll
        for (int j = 0; j < 4; ++j) acc[i][j] = (f32x4){0.f, 0.f, 0.f, 0.f};

    for (int k0 = 0; k0 < K; k0 += 32) {
        __syncthreads();
#pragma unroll
        for (int i = 0; i < 2; ++i) {
            int chunk = t + 256 * i;
            int row = chunk >> 2, seg = chunk & 3;
            int ubase = (wave * 64 + 256 * i) * 8;
            __builtin_amdgcn_global_load_lds(
                (const gu32*)(A + (size_t)(m0 + row) * K + k0 + seg * 8),
                (lu32*)(As + ubase), 16, 0, 0);
            __builtin_amdgcn_global_load_lds(
                (const gu32*)(W + (size_t)(n0 + row) * K + k0 + seg * 8),
                (lu32*)(Bs + ubase), 16, 0, 0);
        }
        __syncthreads();

        bf16x8 af[4], bf[4];
#pragma unroll
        for (int i = 0; i < 4; ++i) {
            af[i] = *(const bf16x8*)(As + (wm + i * 16 + lrow) * 32 + lquad * 8);
            bf[i] = *(const bf16x8*)(Bs + (wn + i * 16 + lrow) * 32 + lquad * 8);
        }
#pragma unroll
        for (int i = 0; i < 4; ++i)
#pragma unroll
            for (int j = 0; j < 4; ++j)
                acc[i][j] = __builtin_amdgcn_mfma_f32_16x16x32_bf16(
                    af[i], bf[j], acc[i][j], 0, 0, 0);
    }
    __syncthreads();                 // K-loop LDS reads done; smem reusable as Lt

    // ---- phase 1 (q/k only): per-row sum of squares over this wave's 64 cols
    float part[4][4];                // [i][r], fully unrolled -> registers
    if (head < NH_ + NKV_) {
#pragma unroll
        for (int i = 0; i < 4; ++i)
#pragma unroll
            for (int r = 0; r < 4; ++r) {
                float p = acc[i][0][r] * acc[i][0][r]
                        + acc[i][1][r] * acc[i][1][r]
                        + acc[i][2][r] * acc[i][2][r]
                        + acc[i][3][r] * acc[i][3][r];
#pragma unroll
                for (int off = 1; off < 16; off <<= 1) p += __shfl_xor(p, off);
                part[i][r] = p;
                if (lrow == 0)
                    rsbuf[half * 128 + wm + i * 16 + lquad * 4 + r] = p;
            }
    }
    __syncthreads();                 // rsbuf visible (uniform barrier)

    // ---- phase 2: normalize+rope -> Lt[row][col], or V -> Lt[col][row] ----
    if (head < NH_ + NKV_) {
        const float* nw = (head < NH_) ? qw : kw;
        float wv[4];
#pragma unroll
        for (int j = 0; j < 4; ++j) wv[j] = nw[wn + j * 16 + lrow];
#pragma unroll
        for (int i = 0; i < 4; ++i)
#pragma unroll
            for (int r = 0; r < 4; ++r) {
                const int rowid = wm + i * 16 + lquad * 4 + r;
                const int s = s0 + rowid;
                const float total = part[i][r] + rsbuf[(half ^ 1) * 128 + rowid];
                const float rs = rsqrtf(total * (1.0f / HD_) + EPS_);
#pragma unroll
                for (int j = 0; j < 4; ++j) {
                    const int d = wn + j * 16 + lrow;
                    const float xn = acc[i][j][r] * rs * wv[j];
                    const float other = __shfl_xor(xn, 1);
                    const float fr = freqs[s * HD_ + (d & ~1)];
                    const float fi = freqs[s * HD_ + (d & ~1) + 1];
                    float out = (d & 1) ? fmaf(xn, fr, other * fi)
                                        : fmaf(xn, fr, -other * fi);
                    if (head < NH_) out *= QSCALE_;
                    Lt[rowid * 136 + d] = f2bf(out);
                }
            }
    } else {                         // V: transpose into Lt[d][s_local]
#pragma unroll
        for (int i = 0; i < 4; ++i)
#pragma unroll
            for (int j = 0; j < 4; ++j)
#pragma unroll
                for (int r = 0; r < 4; ++r)
                    Lt[(wn + j * 16 + lrow) * 136 + wm + i * 16 + lquad * 4 + r]
                        = f2bf(acc[i][j][r]);
    }
    __syncthreads();                 // Lt complete

    // ---- phase 3: coalesced writeout, 256 B per 16-lane group per row ----
    const int g = t >> 4, lx16 = t & 15;
    if (head < NH_) {
        ushort* dst0 = qo + ((size_t)(b * NH_ + head) * S_ + s0) * HD_;
#pragma unroll
        for (int it = 0; it < 8; ++it) {
            const int rowid = it * 16 + g;
            uint4 v = *(const uint4*)(Lt + rowid * 136 + lx16 * 8);
            *(uint4*)(dst0 + (size_t)rowid * HD_ + lx16 * 8) = v;
        }
    } else if (head < NH_ + NKV_) {
        const int kh = head - NH_;
        ushort* dst0 = ko + ((size_t)(b * NKV_ + kh) * S_ + s0) * HD_;
#pragma unroll
        for (int it = 0; it < 8; ++it) {
            const int rowid = it * 16 + g;
            uint4 v = *(const uint4*)(Lt + rowid * 136 + lx16 * 8);
            *(uint4*)(dst0 + (size_t)rowid * HD_ + lx16 * 8) = v;
        }
    } else {                         // V^T rows: d = rowid, s contiguous
        const int vh = head - (NH_ + NKV_);
        ushort* dst0 = vo + ((size_t)(b * NKV_ + vh) * HD_) * S_ + s0;
#pragma unroll
        for (int it = 0; it < 8; ++it) {
            const int rowid = it * 16 + g;
            uint4 v = *(const uint4*)(Lt + rowid * 136 + lx16 * 8);
            *(uint4*)(dst0 + (size_t)rowid * S_ + lx16 * 8) = v;
        }
    }
}

// ------------- K3: causal flash attention, bf16 MFMA ----------------------
// grid (32, NH, B), block 256 = 4 waves. Q tile 64 (16 q-rows/wave), KV 64.
// v4: reg-staged K/V prefetch (no arrays/lambdas), single-buffer LDS,
//     defer-max softmax (THR=8), per-lane l partials, swizzled LDS, setprio.
__global__ __launch_bounds__(256, 3) void flash_attn_mfma(
    const ushort* __restrict__ Q,   // (B,NH,S,HD) bf16, pre-scaled by 1/sqrt(HD)
    const ushort* __restrict__ K,   // (B,NKV,S,HD) bf16
    const ushort* __restrict__ V,   // (B,NKV,HD,S) bf16 -- transposed
    ushort* __restrict__ Y)         // (B,S,NH*HD) bf16
{
    __shared__ __align__(16) ushort Ks[4 * 64 * 32];   // [kstep][kv][32] 16 KB
    __shared__ __align__(16) ushort Vs[2 * 128 * 32];  // [kks][d][32]    16 KB
    __shared__ __align__(16) ushort Ps[4 * 16 * 72];   // per-wave P       9 KB

    const int t = threadIdx.x, w = t >> 6, lane = t & 63;
    const int lx = lane & 15, quad = lane >> 4;
    const int h = blockIdx.y, b = blockIdx.z;
    const int qt = (int)gridDim.x - 1 - (int)blockIdx.x;  // heavy blocks first
    const int q0 = qt * 64;
    const int kvh = h >> 2;
    const int srow = lane >> 2, sseg = lane & 3;          // staging row/seg
    const int wslot = (sseg ^ ((srow >> 1) & 3)) * 8;     // write slot (u16)
    const int rslot = (quad ^ ((lx >> 1) & 3)) * 8;       // read slot (u16)

    const ushort* qb = Q + ((size_t)(b * NH_ + h) * S_ + q0) * HD_;
    const ushort* ksrc = K + ((size_t)(b * NKV_ + kvh) * S_ + w * 16 + srow) * HD_
                           + sseg * 8;
    const ushort* vb = V + ((size_t)(b * NKV_ + kvh) * HD_) * S_;
    const ushort* vsrc0 = vb + (size_t)(w * 16 + srow) * S_ + sseg * 8;
    const ushort* vsrc1 = vb + (size_t)(64 + w * 16 + srow) * S_ + sseg * 8;
    ushort* kdst = Ks + w * 512 + srow * 32 + wslot;            // +i*2048
    ushort* vdst0 = Vs + (w * 16 + srow) * 32 + wslot;          // +kks*4096
    ushort* vdst1 = Vs + (64 + w * 16 + srow) * 32 + wslot;     // +kks*4096

    bf16x8 aq[4];
#pragma unroll
    for (int ks = 0; ks < 4; ++ks)
        aq[ks] = *(const bf16x8*)(qb + (size_t)(w * 16 + lx) * HD_ + ks * 32 + quad * 8);

    f32x4 o[8];
#pragma unroll
    for (int j = 0; j < 8; ++j) o[j] = (f32x4){0.f, 0.f, 0.f, 0.f};
    float mrow[4] = {-INFINITY, -INFINITY, -INFINITY, -INFINITY};
    float lp[4] = {0.f, 0.f, 0.f, 0.f};

    uint4 kr0, kr1, kr2, kr3, vr0, vr1, vr2, vr3;
    kr0 = *(const uint4*)(ksrc +  0);
    kr1 = *(const uint4*)(ksrc + 32);
    kr2 = *(const uint4*)(ksrc + 64);
    kr3 = *(const uint4*)(ksrc + 96);
    vr0 = *(const uint4*)(vsrc0 +  0);
    vr1 = *(const uint4*)(vsrc1 +  0);
    vr2 = *(const uint4*)(vsrc0 + 32);
    vr3 = *(const uint4*)(vsrc1 + 32);

    const int ntiles = qt + 1;
    for (int tk = 0; tk < ntiles; ++tk) {
        const int k0 = tk * 64;
        asm volatile("s_barrier" ::: "memory");
        *(uint4*)(kdst +    0) = kr0;
        *(uint4*)(kdst + 2048) = kr1;
        *(uint4*)(kdst + 4096) = kr2;
        *(uint4*)(kdst + 6144) = kr3;
        *(uint4*)(vdst0 +    0) = vr0;
        *(uint4*)(vdst1 +    0) = vr1;
        *(uint4*)(vdst0 + 4096) = vr2;
        *(uint4*)(vdst1 + 4096) = vr3;
        asm volatile("s_waitcnt lgkmcnt(0)" ::: "memory");
        asm volatile("s_barrier" ::: "memory");

        if (tk + 1 < ntiles) {
            const size_t ko8 = (size_t)(k0 + 64);
            kr0 = *(const uint4*)(ksrc + ko8 * HD_ +  0);
            kr1 = *(const uint4*)(ksrc + ko8 * HD_ + 32);
            kr2 = *(const uint4*)(ksrc + ko8 * HD_ + 64);
            kr3 = *(const uint4*)(ksrc + ko8 * HD_ + 96);
            vr0 = *(const uint4*)(vsrc0 + ko8 +  0);
            vr1 = *(const uint4*)(vsrc1 + ko8 +  0);
            vr2 = *(const uint4*)(vsrc0 + ko8 + 32);
            vr3 = *(const uint4*)(vsrc1 + ko8 + 32);
        }

        f32x4 s[4];
#pragma unroll
        for (int j = 0; j < 4; ++j) s[j] = (f32x4){0.f, 0.f, 0.f, 0.f};
        __builtin_amdgcn_s_setprio(1);
#pragma unroll
        for (int ks = 0; ks < 4; ++ks) {
#pragma unroll
            for (int j = 0; j < 4; ++j) {
                bf16x8 bk = *(const bf16x8*)(Ks + ks * 2048 + (j * 16 + lx) * 32 + rslot);
                s[j] = __builtin_amdgcn_mfma_f32_16x16x32_bf16(aq[ks], bk, s[j], 0, 0, 0);
            }
        }
        __builtin_amdgcn_s_setprio(0);

        const int qrow_base = q0 + w * 16 + quad * 4;
        if (tk == ntiles - 1) {
#pragma unroll
            for (int reg = 0; reg < 4; ++reg) {
                const int qrow = qrow_base + reg;
#pragma unroll
                for (int j = 0; j < 4; ++j)
                    if (k0 + lx + 16 * j > qrow) s[j][reg] = -INFINITY;
            }
        }

        float rmx[4];
        bool need = false;
#pragma unroll
        for (int reg = 0; reg < 4; ++reg) {
            rmx[reg] = fmaxf(fmaxf(s[0][reg], s[1][reg]),
                             fmaxf(s[2][reg], s[3][reg]));
            need |= (rmx[reg] > mrow[reg] + 8.0f);
        }
        if (__any(need)) {
#pragma unroll
            for (int reg = 0; reg < 4; ++reg) {
                float rm = rmx[reg];
#pragma unroll
                for (int off = 1; off < 16; off <<= 1)
                    rm = fmaxf(rm, __shfl_xor(rm, off));
                const float mn = fmaxf(mrow[reg], rm);
                const float alpha = __expf(mrow[reg] - mn);
                mrow[reg] = mn;
                lp[reg] *= alpha;
#pragma unroll
                for (int j = 0; j < 8; ++j) o[j][reg] *= alpha;
            }
        }
#pragma unroll
        for (int reg = 0; reg < 4; ++reg) {
#pragma unroll
            for (int j = 0; j < 4; ++j) {
                const float p = __expf(s[j][reg] - mrow[reg]);
                lp[reg] += p;
                Ps[w * 1152 + (quad * 4 + reg) * 72 + lx + 16 * j] = f2bf(p);
            }
        }

        bf16x8 ap[2];
#pragma unroll
        for (int ks2 = 0; ks2 < 2; ++ks2)
            ap[ks2] = *(const bf16x8*)(Ps + w * 1152 + lx * 72 + ks2 * 32 + quad * 8);
        __builtin_amdgcn_s_setprio(1);
#pragma unroll
        for (int jd = 0; jd < 8; ++jd) {
#pragma unroll
            for (int ks2 = 0; ks2 < 2; ++ks2) {
                bf16x8 bv = *(const bf16x8*)(Vs + ks2 * 4096 + (jd * 16 + lx) * 32 + rslot);
                o[jd] = __builtin_amdgcn_mfma_f32_16x16x32_bf16(ap[ks2], bv, o[jd], 0, 0, 0);
            }
        }
        __builtin_amdgcn_s_setprio(0);
    }

#pragma unroll
    for (int reg = 0; reg < 4; ++reg) {
        float l = lp[reg];
#pragma unroll
        for (int off = 1; off < 16; off <<= 1) l += __shfl_xor(l, off);
        const float inv = 1.0f / l;
        const size_t yb = (size_t)(b * S_ + q0 + w * 16 + quad * 4 + reg) * (NH_ * HD_)
                        + h * HD_ + lx;
#pragma unroll
        for (int jd = 0; jd < 8; ++jd)
            Y[yb + jd * 16] = f2bf(o[jd][reg] * inv);
    }
}

extern "C" void kernel_launch(void* const* d_in, const int* in_sizes, int n_in,
                              void* d_out, int out_size, void* d_ws, size_t ws_size,
                              hipStream_t stream)
{
    const float* x     = (const float*)d_in[0];
    const float* freqs = (const float*)d_in[1];
    const float* wqkv  = (const float*)d_in[2];
    const float* wo    = (const float*)d_in[3];
    const float* qw    = (const float*)d_in[4];
    const float* kw    = (const float*)d_in[5];
    float* out = (float*)d_out;

    // ws layout v4 (fp32 qkv intermediate ELIMINATED; no aliasing between
    // fused-K1 inputs (wqkvbf, xbf) and outputs (qbf/kbf/vtb)):
    //   [0..16.78M)       qbf   (B,NH,S,HD) bf16
    //   [16.78M..20.97M)  kbf   (B,NKV,S,HD) bf16
    //   [20.97M..25.17M)  vtb   (B,NKV,HD,S) bf16 transposed
    //   [25.17M..41.94M)  ybf   (B,S,NH*HD) bf16
    //   [41.94M..50.33M)  wobf
    //   [50.33M..62.91M)  wqkvbf
    //   [83.89M..100.66M) xbf
    char* ws = (char*)d_ws;
    ushort* qbf    = (ushort*)(ws + 0);
    ushort* kbf    = (ushort*)(ws + 16777216);
    ushort* vtb    = (ushort*)(ws + 20971520);
    ushort* ybf    = (ushort*)(ws + 25165824);
    ushort* wobf   = (ushort*)(ws + 41943040);
    ushort* wqkvbf = (ushort*)(ws + 50331648);
    ushort* xbf    = (ushort*)(ws + 83886080);

    pack_bf16<<<(M_ * D_ / 4 + 255) / 256, 256, 0, stream>>>(x, xbf, M_ * D_ / 4);
    pack_bf16<<<(EQKV_ * D_ / 4 + 255) / 256, 256, 0, stream>>>(wqkv, wqkvbf,
                                                                EQKV_ * D_ / 4);
    // K1 fused: qkv GEMM + rmsnorm + rope + scale + bf16 + V^T (no fp32 qkv)
    gemm_qkv_fused<<<dim3(EQKV_ / 128, M_ / 128), 256, 0, stream>>>(
        xbf, wqkvbf, freqs, qw, kw, qbf, kbf, vtb, D_);
    // pack wo (independent; fills the gap while K1 runs)
    pack_bf16<<<(D_ * NH_ * HD_ / 4 + 255) / 256, 256, 0, stream>>>(
        wo, wobf, D_ * NH_ * HD_ / 4);
    // K3: MFMA flash attention -> ybf
    flash_attn_mfma<<<dim3(S_ / 64, NH_, B_), 256, 0, stream>>>(qbf, kbf, vtb, ybf);
    // K4: out = y @ wo^T  (bf16 MFMA)
    gemm_nt_bf16<<<dim3(D_ / 128, M_ / 128), 256, 0, stream>>>(
        ybf, wobf, out, M_, D_, NH_ * HD_);
}

// Round 5
// 349.523 us; speedup vs baseline: 1.6475x; 1.0477x over previous
//
#include <hip/hip_runtime.h>
#include <math.h>

constexpr int B_ = 2, S_ = 2048, D_ = 2048, NH_ = 16, NKV_ = 4, HD_ = 128;
constexpr int EQKV_ = (NH_ + 2 * NKV_) * HD_;   // 3072
constexpr int M_ = B_ * S_;                     // 4096
constexpr float EPS_ = 1e-6f;
constexpr float QSCALE_ = 0.08838834764831845f; // 1/sqrt(HD)

typedef __attribute__((ext_vector_type(8))) short bf16x8;
typedef __attribute__((ext_vector_type(4))) float f32x4;
typedef __attribute__((address_space(1))) unsigned int gu32;
typedef __attribute__((address_space(3))) unsigned int lu32;

__device__ inline ushort f2bf(float f) {   // RNE fp32->bf16 (finite inputs)
    unsigned u = __float_as_uint(f);
    return (ushort)((u + 0x7FFF + ((u >> 16) & 1)) >> 16);
}

// ---------------- pack: fp32 -> bf16, float4 per thread --------------------
__global__ __launch_bounds__(256) void pack_bf16(
    const float* __restrict__ in, ushort* __restrict__ out, int n4)
{
    int i = blockIdx.x * 256 + threadIdx.x;
    if (i >= n4) return;
    float4 f = ((const float4*)in)[i];
    ushort4 u;
    u.x = f2bf(f.x); u.y = f2bf(f.y); u.z = f2bf(f.z); u.w = f2bf(f.w);
    ((ushort4*)out)[i] = u;
}

// ------- K4: C[m,n] = sum_k A[m,k]*W[n,k], bf16 MFMA (m97 structure) -------
__global__ __launch_bounds__(256) void gemm_nt_bf16(
    const ushort* __restrict__ A, const ushort* __restrict__ W,
    float* __restrict__ C, int M, int N, int K)
{
    __shared__ ushort As[128 * 32];
    __shared__ ushort Bs[128 * 32];
    const int t = threadIdx.x;
    const int wave = t >> 6, lane = t & 63;
    const int m0 = blockIdx.y * 128, n0 = blockIdx.x * 128;
    const int wm = (wave >> 1) * 64, wn = (wave & 1) * 64;
    const int lrow = lane & 15, lquad = lane >> 4;

    f32x4 acc[4][4];
#pragma unroll
    for (int i = 0; i < 4; ++i)
#pragma unroll
        for (int j = 0; j < 4; ++j) acc[i][j] = (f32x4){0.f, 0.f, 0.f, 0.f};

    for (int k0 = 0; k0 < K; k0 += 32) {
        __syncthreads();
#pragma unroll
        for (int i = 0; i < 2; ++i) {
            int chunk = t + 256 * i;
            int row = chunk >> 2, seg = chunk & 3;
            int ubase = (wave * 64 + 256 * i) * 8;
            __builtin_amdgcn_global_load_lds(
                (const gu32*)(A + (size_t)(m0 + row) * K + k0 + seg * 8),
                (lu32*)(As + ubase), 16, 0, 0);
            __builtin_amdgcn_global_load_lds(
                (const gu32*)(W + (size_t)(n0 + row) * K + k0 + seg * 8),
                (lu32*)(Bs + ubase), 16, 0, 0);
        }
        __syncthreads();

        bf16x8 af[4], bf[4];
#pragma unroll
        for (int i = 0; i < 4; ++i) {
            af[i] = *(const bf16x8*)(As + (wm + i * 16 + lrow) * 32 + lquad * 8);
            bf[i] = *(const bf16x8*)(Bs + (wn + i * 16 + lrow) * 32 + lquad * 8);
        }
#pragma unroll
        for (int i = 0; i < 4; ++i)
#pragma unroll
            for (int j = 0; j < 4; ++j)
                acc[i][j] = __builtin_amdgcn_mfma_f32_16x16x32_bf16(
                    af[i], bf[j], acc[i][j], 0, 0, 0);
    }
#pragma unroll
    for (int i = 0; i < 4; ++i)
#pragma unroll
        for (int j = 0; j < 4; ++j) {
            float* cp = C + (size_t)(m0 + wm + i * 16 + lquad * 4) * N
                          + n0 + wn + j * 16 + lrow;
#pragma unroll
            for (int r = 0; r < 4; ++r) cp[(size_t)r * N] = acc[i][j][r];
        }
}

// --- K1 fused: qkv GEMM + RMSNorm + RoPE + scale + bf16 + V^T, no fp32 C ---
__global__ __launch_bounds__(256) void gemm_qkv_fused(
    const ushort* __restrict__ A,   // xbf (M,K) bf16
    const ushort* __restrict__ W,   // wqkvbf (EQKV,K) bf16
    const float* __restrict__ freqs,
    const float* __restrict__ qw, const float* __restrict__ kw,
    ushort* __restrict__ qo, ushort* __restrict__ ko, ushort* __restrict__ vo,
    int K)
{
    __shared__ __align__(16) ushort smem[128 * 136];  // As|Bs during K-loop; Lt after
    __shared__ float rsbuf[256];
    ushort* As = smem;            // 128*32
    ushort* Bs = smem + 4096;     // 128*32
    ushort* Lt = smem;            // [128][136] u16 staging tile (post-loop)

    const int t = threadIdx.x;
    const int wave = t >> 6, lane = t & 63;
    const int m0 = blockIdx.y * 128, n0 = blockIdx.x * 128;
    const int wm = (wave >> 1) * 64, wn = (wave & 1) * 64;
    const int half = wave & 1;                 // which 64-col half this wave owns
    const int lrow = lane & 15, lquad = lane >> 4;
    const int head = n0 >> 7;                  // block-uniform: [0,16)q [16,20)k [20,24)v
    const int b = m0 >> 11, s0 = m0 & (S_ - 1);

    f32x4 acc[4][4];
#pragma unroll
    for (int i = 0; i < 4; ++i)
#pragma unroll
        for (int j = 0; j < 4; ++j) acc[i][j] = (f32x4){0.f, 0.f, 0.f, 0.f};

    for (int k0 = 0; k0 < K; k0 += 32) {
        __syncthreads();
#pragma unroll
        for (int i = 0; i < 2; ++i) {
            int chunk = t + 256 * i;
            int row = chunk >> 2, seg = chunk & 3;
            int ubase = (wave * 64 + 256 * i) * 8;
            __builtin_amdgcn_global_load_lds(
                (const gu32*)(A + (size_t)(m0 + row) * K + k0 + seg * 8),
                (lu32*)(As + ubase), 16, 0, 0);
            __builtin_amdgcn_global_load_lds(
                (const gu32*)(W + (size_t)(n0 + row) * K + k0 + seg * 8),
                (lu32*)(Bs + ubase), 16, 0, 0);
        }
        __syncthreads();

        bf16x8 af[4], bf[4];
#pragma unroll
        for (int i = 0; i < 4; ++i) {
            af[i] = *(const bf16x8*)(As + (wm + i * 16 + lrow) * 32 + lquad * 8);
            bf[i] = *(const bf16x8*)(Bs + (wn + i * 16 + lrow) * 32 + lquad * 8);
        }
#pragma unroll
        for (int i = 0; i < 4; ++i)
#pragma unroll
            for (int j = 0; j < 4; ++j)
                acc[i][j] = __builtin_amdgcn_mfma_f32_16x16x32_bf16(
                    af[i], bf[j], acc[i][j], 0, 0, 0);
    }
    __syncthreads();                 // K-loop LDS reads done; smem reusable as Lt

    float part[4][4];
    if (head < NH_ + NKV_) {
#pragma unroll
        for (int i = 0; i < 4; ++i)
#pragma unroll
            for (int r = 0; r < 4; ++r) {
                float p = acc[i][0][r] * acc[i][0][r]
                        + acc[i][1][r] * acc[i][1][r]
                        + acc[i][2][r] * acc[i][2][r]
                        + acc[i][3][r] * acc[i][3][r];
#pragma unroll
                for (int off = 1; off < 16; off <<= 1) p += __shfl_xor(p, off);
                part[i][r] = p;
                if (lrow == 0)
                    rsbuf[half * 128 + wm + i * 16 + lquad * 4 + r] = p;
            }
    }
    __syncthreads();

    if (head < NH_ + NKV_) {
        const float* nw = (head < NH_) ? qw : kw;
        float wv[4];
#pragma unroll
        for (int j = 0; j < 4; ++j) wv[j] = nw[wn + j * 16 + lrow];
#pragma unroll
        for (int i = 0; i < 4; ++i)
#pragma unroll
            for (int r = 0; r < 4; ++r) {
                const int rowid = wm + i * 16 + lquad * 4 + r;
                const int s = s0 + rowid;
                const float total = part[i][r] + rsbuf[(half ^ 1) * 128 + rowid];
                const float rs = rsqrtf(total * (1.0f / HD_) + EPS_);
#pragma unroll
                for (int j = 0; j < 4; ++j) {
                    const int d = wn + j * 16 + lrow;
                    const float xn = acc[i][j][r] * rs * wv[j];
                    const float other = __shfl_xor(xn, 1);
                    const float fr = freqs[s * HD_ + (d & ~1)];
                    const float fi = freqs[s * HD_ + (d & ~1) + 1];
                    float out = (d & 1) ? fmaf(xn, fr, other * fi)
                                        : fmaf(xn, fr, -other * fi);
                    if (head < NH_) out *= QSCALE_;
                    Lt[rowid * 136 + d] = f2bf(out);
                }
            }
    } else {                         // V: transpose into Lt[d][s_local]
#pragma unroll
        for (int i = 0; i < 4; ++i)
#pragma unroll
            for (int j = 0; j < 4; ++j)
#pragma unroll
                for (int r = 0; r < 4; ++r)
                    Lt[(wn + j * 16 + lrow) * 136 + wm + i * 16 + lquad * 4 + r]
                        = f2bf(acc[i][j][r]);
    }
    __syncthreads();

    const int g = t >> 4, lx16 = t & 15;
    if (head < NH_) {
        ushort* dst0 = qo + ((size_t)(b * NH_ + head) * S_ + s0) * HD_;
#pragma unroll
        for (int it = 0; it < 8; ++it) {
            const int rowid = it * 16 + g;
            uint4 v = *(const uint4*)(Lt + rowid * 136 + lx16 * 8);
            *(uint4*)(dst0 + (size_t)rowid * HD_ + lx16 * 8) = v;
        }
    } else if (head < NH_ + NKV_) {
        const int kh = head - NH_;
        ushort* dst0 = ko + ((size_t)(b * NKV_ + kh) * S_ + s0) * HD_;
#pragma unroll
        for (int it = 0; it < 8; ++it) {
            const int rowid = it * 16 + g;
            uint4 v = *(const uint4*)(Lt + rowid * 136 + lx16 * 8);
            *(uint4*)(dst0 + (size_t)rowid * HD_ + lx16 * 8) = v;
        }
    } else {                         // V^T rows: d = rowid, s contiguous
        const int vh = head - (NH_ + NKV_);
        ushort* dst0 = vo + ((size_t)(b * NKV_ + vh) * HD_) * S_ + s0;
#pragma unroll
        for (int it = 0; it < 8; ++it) {
            const int rowid = it * 16 + g;
            uint4 v = *(const uint4*)(Lt + rowid * 136 + lx16 * 8);
            *(uint4*)(dst0 + (size_t)rowid * S_ + lx16 * 8) = v;
        }
    }
}

// ------------- K3: causal flash attention, bf16 MFMA, KV-SPLIT ------------
// grid (48, NH, B): gx<32 -> split halves of heavy q-tiles qt=16..31
// (half KV range each, partial O/m/l out); gx>=32 -> light q-tiles qt=15..0
// (direct Y). Max serial chain: 16 KV-tile iterations everywhere.
__global__ __launch_bounds__(256, 3) void flash_attn_mfma(
    const ushort* __restrict__ Q,   // (B,NH,S,HD) bf16, pre-scaled
    const ushort* __restrict__ K,   // (B,NKV,S,HD) bf16
    const ushort* __restrict__ V,   // (B,NKV,HD,S) bf16 -- transposed
    ushort* __restrict__ Y,         // (B,S,NH*HD) bf16
    float* __restrict__ OP,         // [bh][st<16][half][64][128] f32 partial O
    float* __restrict__ ML)         // [bh][st][half][2][64] f32 (m, l)
{
    __shared__ __align__(16) ushort Ks[4 * 64 * 32];   // 16 KB
    __shared__ __align__(16) ushort Vs[2 * 128 * 32];  // 16 KB
    __shared__ __align__(16) ushort Ps[4 * 16 * 72];   //  9 KB

    const int t = threadIdx.x, w = t >> 6, lane = t & 63;
    const int lx = lane & 15, quad = lane >> 4;
    const int h = blockIdx.y, b = blockIdx.z;

    // ---- work decode: heavy split blocks first ----
    const int gx = blockIdx.x;
    int qt, halfsel, tk0, tk1;
    bool split;
    if (gx < 32) {
        split = true;
        qt = 31 - (gx >> 1);
        halfsel = gx & 1;
        const int nt = qt + 1, nt0 = nt >> 1;
        tk0 = halfsel ? nt0 : 0;
        tk1 = halfsel ? nt : nt0;
    } else {
        split = false;
        qt = 47 - gx;                  // 15 .. 0
        halfsel = 0;
        tk0 = 0;
        tk1 = qt + 1;
    }
    const int q0 = qt * 64;
    const int kvh = h >> 2;
    const int srow = lane >> 2, sseg = lane & 3;
    const int wslot = (sseg ^ ((srow >> 1) & 3)) * 8;
    const int rslot = (quad ^ ((lx >> 1) & 3)) * 8;

    const ushort* qb = Q + ((size_t)(b * NH_ + h) * S_ + q0) * HD_;
    const ushort* ksrc = K + ((size_t)(b * NKV_ + kvh) * S_ + w * 16 + srow) * HD_
                           + sseg * 8;
    const ushort* vb = V + ((size_t)(b * NKV_ + kvh) * HD_) * S_;
    const ushort* vsrc0 = vb + (size_t)(w * 16 + srow) * S_ + sseg * 8;
    const ushort* vsrc1 = vb + (size_t)(64 + w * 16 + srow) * S_ + sseg * 8;
    ushort* kdst = Ks + w * 512 + srow * 32 + wslot;
    ushort* vdst0 = Vs + (w * 16 + srow) * 32 + wslot;
    ushort* vdst1 = Vs + (64 + w * 16 + srow) * 32 + wslot;

    bf16x8 aq[4];
#pragma unroll
    for (int ks = 0; ks < 4; ++ks)
        aq[ks] = *(const bf16x8*)(qb + (size_t)(w * 16 + lx) * HD_ + ks * 32 + quad * 8);

    f32x4 o[8];
#pragma unroll
    for (int j = 0; j < 8; ++j) o[j] = (f32x4){0.f, 0.f, 0.f, 0.f};
    float mrow[4] = {-INFINITY, -INFINITY, -INFINITY, -INFINITY};
    float lp[4] = {0.f, 0.f, 0.f, 0.f};

    uint4 kr0, kr1, kr2, kr3, vr0, vr1, vr2, vr3;
    {
        const size_t kb0 = (size_t)tk0 * 64;
        kr0 = *(const uint4*)(ksrc + kb0 * HD_ +  0);
        kr1 = *(const uint4*)(ksrc + kb0 * HD_ + 32);
        kr2 = *(const uint4*)(ksrc + kb0 * HD_ + 64);
        kr3 = *(const uint4*)(ksrc + kb0 * HD_ + 96);
        vr0 = *(const uint4*)(vsrc0 + kb0 +  0);
        vr1 = *(const uint4*)(vsrc1 + kb0 +  0);
        vr2 = *(const uint4*)(vsrc0 + kb0 + 32);
        vr3 = *(const uint4*)(vsrc1 + kb0 + 32);
    }

    for (int tk = tk0; tk < tk1; ++tk) {
        const int k0 = tk * 64;
        asm volatile("s_barrier" ::: "memory");
        *(uint4*)(kdst +    0) = kr0;
        *(uint4*)(kdst + 2048) = kr1;
        *(uint4*)(kdst + 4096) = kr2;
        *(uint4*)(kdst + 6144) = kr3;
        *(uint4*)(vdst0 +    0) = vr0;
        *(uint4*)(vdst1 +    0) = vr1;
        *(uint4*)(vdst0 + 4096) = vr2;
        *(uint4*)(vdst1 + 4096) = vr3;
        asm volatile("s_waitcnt lgkmcnt(0)" ::: "memory");
        asm volatile("s_barrier" ::: "memory");

        if (tk + 1 < tk1) {
            const size_t ko8 = (size_t)(k0 + 64);
            kr0 = *(const uint4*)(ksrc + ko8 * HD_ +  0);
            kr1 = *(const uint4*)(ksrc + ko8 * HD_ + 32);
            kr2 = *(const uint4*)(ksrc + ko8 * HD_ + 64);
            kr3 = *(const uint4*)(ksrc + ko8 * HD_ + 96);
            vr0 = *(const uint4*)(vsrc0 + ko8 +  0);
            vr1 = *(const uint4*)(vsrc1 + ko8 +  0);
            vr2 = *(const uint4*)(vsrc0 + ko8 + 32);
            vr3 = *(const uint4*)(vsrc1 + ko8 + 32);
        }

        f32x4 s[4];
#pragma unroll
        for (int j = 0; j < 4; ++j) s[j] = (f32x4){0.f, 0.f, 0.f, 0.f};
        __builtin_amdgcn_s_setprio(1);
#pragma unroll
        for (int ks = 0; ks < 4; ++ks) {
#pragma unroll
            for (int j = 0; j < 4; ++j) {
                bf16x8 bk = *(const bf16x8*)(Ks + ks * 2048 + (j * 16 + lx) * 32 + rslot);
                s[j] = __builtin_amdgcn_mfma_f32_16x16x32_bf16(aq[ks], bk, s[j], 0, 0, 0);
            }
        }
        __builtin_amdgcn_s_setprio(0);

        const int qrow_base = q0 + w * 16 + quad * 4;
        if (tk == qt) {                     // diagonal tile only
#pragma unroll
            for (int reg = 0; reg < 4; ++reg) {
                const int qrow = qrow_base + reg;
#pragma unroll
                for (int j = 0; j < 4; ++j)
                    if (k0 + lx + 16 * j > qrow) s[j][reg] = -INFINITY;
            }
        }

        float rmx[4];
        bool need = false;
#pragma unroll
        for (int reg = 0; reg < 4; ++reg) {
            rmx[reg] = fmaxf(fmaxf(s[0][reg], s[1][reg]),
                             fmaxf(s[2][reg], s[3][reg]));
            need |= (rmx[reg] > mrow[reg] + 8.0f);
        }
        if (__any(need)) {
#pragma unroll
            for (int reg = 0; reg < 4; ++reg) {
                float rm = rmx[reg];
#pragma unroll
                for (int off = 1; off < 16; off <<= 1)
                    rm = fmaxf(rm, __shfl_xor(rm, off));
                const float mn = fmaxf(mrow[reg], rm);
                const float alpha = __expf(mrow[reg] - mn);
                mrow[reg] = mn;
                lp[reg] *= alpha;
#pragma unroll
                for (int j = 0; j < 8; ++j) o[j][reg] *= alpha;
            }
        }
#pragma unroll
        for (int reg = 0; reg < 4; ++reg) {
#pragma unroll
            for (int j = 0; j < 4; ++j) {
                const float p = __expf(s[j][reg] - mrow[reg]);
                lp[reg] += p;
                Ps[w * 1152 + (quad * 4 + reg) * 72 + lx + 16 * j] = f2bf(p);
            }
        }

        bf16x8 ap[2];
#pragma unroll
        for (int ks2 = 0; ks2 < 2; ++ks2)
            ap[ks2] = *(const bf16x8*)(Ps + w * 1152 + lx * 72 + ks2 * 32 + quad * 8);
        __builtin_amdgcn_s_setprio(1);
#pragma unroll
        for (int jd = 0; jd < 8; ++jd) {
#pragma unroll
            for (int ks2 = 0; ks2 < 2; ++ks2) {
                bf16x8 bv = *(const bf16x8*)(Vs + ks2 * 4096 + (jd * 16 + lx) * 32 + rslot);
                o[jd] = __builtin_amdgcn_mfma_f32_16x16x32_bf16(ap[ks2], bv, o[jd], 0, 0, 0);
            }
        }
        __builtin_amdgcn_s_setprio(0);
    }

    // ---- epilogue ----
#pragma unroll
    for (int reg = 0; reg < 4; ++reg) {
        float l = lp[reg];
#pragma unroll
        for (int off = 1; off < 16; off <<= 1) l += __shfl_xor(l, off);
        lp[reg] = l;                        // reduced l, all lanes
    }
    if (!split) {
#pragma unroll
        for (int reg = 0; reg < 4; ++reg) {
            const float inv = 1.0f / lp[reg];
            const size_t yb = (size_t)(b * S_ + q0 + w * 16 + quad * 4 + reg) * (NH_ * HD_)
                            + h * HD_ + lx;
#pragma unroll
            for (int jd = 0; jd < 8; ++jd)
                Y[yb + jd * 16] = f2bf(o[jd][reg] * inv);
        }
    } else {
        const int bh = b * NH_ + h;
        const int st = qt - 16;
        const size_t pidx = (size_t)(bh * 16 + st) * 2 + halfsel;
        float* mlb = ML + pidx * 128;
#pragma unroll
        for (int reg = 0; reg < 4; ++reg) {
            const int row = w * 16 + quad * 4 + reg;
            if (lx == 0) {                  // one lane per row writes m, l
                mlb[row] = mrow[reg];
                mlb[64 + row] = lp[reg];
            }
            float* ob = OP + (pidx * 64 + row) * 128 + lx;
#pragma unroll
            for (int jd = 0; jd < 8; ++jd)
                ob[jd * 16] = o[jd][reg];
        }
    }
}

// ------------- K3b: merge the two KV-halves of heavy q-tiles --------------
__global__ __launch_bounds__(256) void attn_combine(
    const float* __restrict__ OP, const float* __restrict__ ML,
    ushort* __restrict__ Y)
{
    const int st = blockIdx.x, h = blockIdx.y, b = blockIdx.z;
    const int bh = b * NH_ + h;
    const int d = threadIdx.x & 127, rg = threadIdx.x >> 7;
    const size_t p0 = (size_t)(bh * 16 + st) * 2;
    const float* ml0 = ML + p0 * 128;
    const float* ml1 = ML + (p0 + 1) * 128;
    const float* o0 = OP + p0 * 64 * 128;
    const float* o1 = OP + (p0 + 1) * 64 * 128;
    const int q0 = (16 + st) * 64;
#pragma unroll
    for (int r = rg; r < 64; r += 2) {
        const float m0 = ml0[r], l0 = ml0[64 + r];
        const float m1 = ml1[r], l1 = ml1[64 + r];
        const float m = fmaxf(m0, m1);
        const float w0 = __expf(m0 - m), w1 = __expf(m1 - m);
        const float inv = 1.0f / (l0 * w0 + l1 * w1);
        const float v = (o0[r * 128 + d] * w0 + o1[r * 128 + d] * w1) * inv;
        Y[((size_t)(b * S_ + q0 + r)) * (NH_ * HD_) + h * HD_ + d] = f2bf(v);
    }
}

extern "C" void kernel_launch(void* const* d_in, const int* in_sizes, int n_in,
                              void* d_out, int out_size, void* d_ws, size_t ws_size,
                              hipStream_t stream)
{
    const float* x     = (const float*)d_in[0];
    const float* freqs = (const float*)d_in[1];
    const float* wqkv  = (const float*)d_in[2];
    const float* wo    = (const float*)d_in[3];
    const float* qw    = (const float*)d_in[4];
    const float* kw    = (const float*)d_in[5];
    float* out = (float*)d_out;

    // ws layout v5:
    //   [0..16.78M)       qbf   (B,NH,S,HD) bf16
    //   [16.78M..20.97M)  kbf   (B,NKV,S,HD) bf16
    //   [20.97M..25.17M)  vtb   (B,NKV,HD,S) bf16 transposed
    //   [25.17M..41.94M)  ybf   (B,S,NH*HD) bf16
    //   [41.94M..50.33M)  wobf
    //   [50.33M..62.91M)  wqkvbf (dead after K1) -+
    //   [83.89M..100.66M) xbf    (dead after K1) -+-> reused by attn partials:
    //   [50.33M..83.89M)  OP: 32bh x 16st x 2half x 64 x 128 f32 (33.55M)
    //   [83.89M..84.93M)  ML: 32bh x 16st x 2half x 2 x 64 f32  (1.05M)
    char* ws = (char*)d_ws;
    ushort* qbf    = (ushort*)(ws + 0);
    ushort* kbf    = (ushort*)(ws + 16777216);
    ushort* vtb    = (ushort*)(ws + 20971520);
    ushort* ybf    = (ushort*)(ws + 25165824);
    ushort* wobf   = (ushort*)(ws + 41943040);
    ushort* wqkvbf = (ushort*)(ws + 50331648);
    ushort* xbf    = (ushort*)(ws + 83886080);
    float*  OP     = (float*)(ws + 50331648);
    float*  ML     = (float*)(ws + 83886080);

    pack_bf16<<<(M_ * D_ / 4 + 255) / 256, 256, 0, stream>>>(x, xbf, M_ * D_ / 4);
    pack_bf16<<<(EQKV_ * D_ / 4 + 255) / 256, 256, 0, stream>>>(wqkv, wqkvbf,
                                                                EQKV_ * D_ / 4);
    // K1 fused: qkv GEMM + rmsnorm + rope + scale + bf16 + V^T
    gemm_qkv_fused<<<dim3(EQKV_ / 128, M_ / 128), 256, 0, stream>>>(
        xbf, wqkvbf, freqs, qw, kw, qbf, kbf, vtb, D_);
    // pack wo (independent)
    pack_bf16<<<(D_ * NH_ * HD_ / 4 + 255) / 256, 256, 0, stream>>>(
        wo, wobf, D_ * NH_ * HD_ / 4);
    // K3: KV-split flash attention (heavy tiles split in 2) -> ybf / partials
    flash_attn_mfma<<<dim3(48, NH_, B_), 256, 0, stream>>>(qbf, kbf, vtb, ybf,
                                                           OP, ML);
    // K3b: merge heavy-tile halves -> ybf rows 1024..2047 per (b,h)
    attn_combine<<<dim3(16, NH_, B_), 256, 0, stream>>>(OP, ML, ybf);
    // K4: out = y @ wo^T  (bf16 MFMA)
    gemm_nt_bf16<<<dim3(D_ / 128, M_ / 128), 256, 0, stream>>>(
        ybf, wobf, out, M_, D_, NH_ * HD_);
}